// Round 1
// baseline (587.147 us; speedup 1.0000x reference)
//
#include <hip/hip_runtime.h>
#include <hip/hip_bf16.h>

typedef float  f32x4 __attribute__((ext_vector_type(4)));
typedef short  s16x8 __attribute__((ext_vector_type(8)));

#define MEMH   256        // mem_dim
#define MSGD   512        // msg_dim
#define G3     768        // 3*H
#define W_IH_ELEMS (G3*MSGD)        // 393216
#define W_HH_ELEMS (G3*MEMH)        // 196608
#define W_TOT_ELEMS (W_IH_ELEMS + W_HH_ELEMS)  // 589824

static __device__ __forceinline__ short f2bf(float x) {
    __hip_bfloat16 b = __float2bfloat16(x);
    return __builtin_bit_cast(short, b);
}
static __device__ __forceinline__ float bf2f(short s) {
    unsigned int u = ((unsigned int)(unsigned short)s) << 16;
    return __builtin_bit_cast(float, u);
}
static __device__ __forceinline__ float sigf(float x) {
    return 1.f / (1.f + __expf(-x));
}
static __device__ __forceinline__ float tanh_fast(float x) {
    float e = __expf(-2.f * fabsf(x));
    float t = (1.f - e) / (1.f + e);
    return copysignf(t, x);
}

// ---------------------------------------------------------------- copy kernel
__global__ void smu_copy_kernel(const float4* __restrict__ mem,
                                const float4* __restrict__ lu,
                                float4* __restrict__ out_mem,
                                float4* __restrict__ out_lu,
                                long n_mem4, long n_lu4) {
    long i = (long)blockIdx.x * blockDim.x + threadIdx.x;
    long stride = (long)gridDim.x * blockDim.x;
    long total = n_mem4 + n_lu4;
    for (; i < total; i += stride) {
        if (i < n_mem4) out_mem[i] = mem[i];
        else            out_lu[i - n_mem4] = lu[i - n_mem4];
    }
}

// --------------------------------------------------- weight fp32->bf16 kernel
__global__ void smu_cvtw_kernel(const float* __restrict__ wih,
                                const float* __restrict__ whh,
                                short* __restrict__ o) {
    int i = blockIdx.x * blockDim.x + threadIdx.x;
    if (i < W_IH_ELEMS)       o[i] = f2bf(wih[i]);
    else if (i < W_TOT_ELEMS) o[i] = f2bf(whh[i - W_IH_ELEMS]);
}

// ------------------------------------------------------------ B-frag loader
template<bool USE_WS>
static __device__ __forceinline__ s16x8 load_b(const float* __restrict__ Wf,
                                               const short* __restrict__ Wb,
                                               int row, int ldk, int kofs) {
    if constexpr (USE_WS) {
        return *(const s16x8*)(Wb + (size_t)row * ldk + kofs);
    } else {
        const float4* p = (const float4*)(Wf + (size_t)row * ldk + kofs);
        float4 x = p[0], y = p[1];
        s16x8 s;
        s[0]=f2bf(x.x); s[1]=f2bf(x.y); s[2]=f2bf(x.z); s[3]=f2bf(x.w);
        s[4]=f2bf(y.x); s[5]=f2bf(y.y); s[6]=f2bf(y.z); s[7]=f2bf(y.w);
        return s;
    }
}

// --------------------------------------------------------------- fused GRU+LN
// Block: 512 threads (8 waves), BM=32 rows. Each block computes all 1536
// accumulator columns (gi 768 + gh 768) for its 32 rows; wave w owns n16-tiles
// {w+8i, i=0..5} so r/z/n tiles of the same j live in the same wave/lane/reg.
// LDS layout:
//   [0, 33280)        : A_msg bf16 32x512 (pitch 1024B, XOR swizzle) during GEMM,
//                       reused as O fp32 32x260 (pitch 1040B) in epilogue
//   [33280, 49664)    : A_h bf16 32x256 (pitch 512B, XOR swizzle)
template<bool USE_WS>
__global__ __launch_bounds__(512)
void smu_gru_kernel(const int*   __restrict__ ids,
                    const float* __restrict__ msg,
                    const float* __restrict__ ts,
                    const float* __restrict__ memory,
                    const float* __restrict__ W_ih,
                    const float* __restrict__ W_hh,
                    const float* __restrict__ b_ih,
                    const float* __restrict__ b_hh,
                    const float* __restrict__ gamma,
                    const float* __restrict__ beta,
                    const short* __restrict__ wsw,
                    float* __restrict__ out_mem,
                    float* __restrict__ out_lu) {
    __shared__ __align__(16) unsigned char lds[33280 + 32*MEMH*2];
    const int tid  = threadIdx.x;
    const int base = blockIdx.x * 32;

    // ---- stage A_msg: 32x512 f32 -> bf16 (2048 8-elem units, 4 per thread)
    {
        const float4* src = (const float4*)(msg + (size_t)base * MSGD);
        #pragma unroll
        for (int it = 0; it < 4; ++it) {
            int u = tid + 512 * it;          // 0..2047
            int row = u >> 6;                // 64 units per row
            float4 a = src[2*u], b = src[2*u + 1];
            s16x8 s;
            s[0]=f2bf(a.x); s[1]=f2bf(a.y); s[2]=f2bf(a.z); s[3]=f2bf(a.w);
            s[4]=f2bf(b.x); s[5]=f2bf(b.y); s[6]=f2bf(b.z); s[7]=f2bf(b.w);
            int byte = (u * 16) ^ ((row & 7) << 4);   // u*16 == row*1024 + c8*16
            *(s16x8*)(lds + byte) = s;
        }
        // ---- stage A_h (gather): 32x256 (1024 units, 2 per thread)
        #pragma unroll
        for (int it = 0; it < 2; ++it) {
            int u = tid + 512 * it;          // 0..1023
            int row = u >> 5;                // 32 units per row
            int c8  = u & 31;
            int id  = ids[base + row];
            const float4* hs = (const float4*)(memory + (size_t)id * MEMH + c8 * 8);
            float4 a = hs[0], b = hs[1];
            s16x8 s;
            s[0]=f2bf(a.x); s[1]=f2bf(a.y); s[2]=f2bf(a.z); s[3]=f2bf(a.w);
            s[4]=f2bf(b.x); s[5]=f2bf(b.y); s[6]=f2bf(b.z); s[7]=f2bf(b.w);
            int byte = 33280 + ((u * 16) ^ ((row & 7) << 4));  // u*16 == row*512 + c8*16
            *(s16x8*)(lds + byte) = s;
        }
    }
    __syncthreads();

    const int lane = tid & 63;
    const int w    = tid >> 6;
    const int lr   = lane & 15;
    const int lk8  = (lane >> 4) * 8;   // k element offset within 32-wide ktile
    const int sw   = (lr & 7) << 4;     // row swizzle (same for row lr and 16+lr)

    f32x4 gi[2][6] = {};
    f32x4 gh[2][6] = {};

    // ---- GEMM 1: gi += msg @ W_ih^T  (K = 512 -> 16 ktiles)
    for (int k = 0; k < 16; ++k) {
        int cb = (k * 32 + lk8) * 2;
        s16x8 a0 = *(const s16x8*)(lds + ((lr * 1024 + cb) ^ sw));
        s16x8 a1 = *(const s16x8*)(lds + (((16 + lr) * 1024 + cb) ^ sw));
        #pragma unroll
        for (int i = 0; i < 6; ++i) {
            int t = w + 8 * i;
            s16x8 b = load_b<USE_WS>(W_ih, wsw, t * 16 + lr, MSGD, k * 32 + lk8);
            gi[0][i] = __builtin_amdgcn_mfma_f32_16x16x32_bf16(a0, b, gi[0][i], 0, 0, 0);
            gi[1][i] = __builtin_amdgcn_mfma_f32_16x16x32_bf16(a1, b, gi[1][i], 0, 0, 0);
        }
    }
    // ---- GEMM 2: gh += h @ W_hh^T  (K = 256 -> 8 ktiles)
    for (int k = 0; k < 8; ++k) {
        int cb = (k * 32 + lk8) * 2;
        s16x8 a0 = *(const s16x8*)(lds + 33280 + ((lr * 512 + cb) ^ sw));
        s16x8 a1 = *(const s16x8*)(lds + 33280 + (((16 + lr) * 512 + cb) ^ sw));
        #pragma unroll
        for (int i = 0; i < 6; ++i) {
            int t = w + 8 * i;
            s16x8 b = load_b<USE_WS>(W_hh, wsw + W_IH_ELEMS, t * 16 + lr, MEMH, k * 32 + lk8);
            gh[0][i] = __builtin_amdgcn_mfma_f32_16x16x32_bf16(a0, b, gh[0][i], 0, 0, 0);
            gh[1][i] = __builtin_amdgcn_mfma_f32_16x16x32_bf16(a1, b, gh[1][i], 0, 0, 0);
        }
    }

    __syncthreads();   // A_msg reads done before O overwrites the region

    // ---- gate epilogue: all wave-local. C layout: col=lane&15, row=(lane>>4)*4+q
    const int lq = (lane >> 4) * 4;
    #pragma unroll
    for (int m = 0; m < 2; ++m) {
        #pragma unroll
        for (int d = 0; d < 2; ++d) {
            int j = (w + 8 * d) * 16 + lr;         // 0..255
            float bihr = b_ih[j],        bhhr = b_hh[j];
            float bihz = b_ih[256 + j],  bhhz = b_hh[256 + j];
            float bihn = b_ih[512 + j],  bhhn = b_hh[512 + j];
            #pragma unroll
            for (int q = 0; q < 4; ++q) {
                int row = m * 16 + lq + q;
                float r = sigf(gi[m][d][q]     + gh[m][d][q]     + bihr + bhhr);
                float z = sigf(gi[m][2 + d][q] + gh[m][2 + d][q] + bihz + bhhz);
                float n = tanh_fast(gi[m][4 + d][q] + bihn + r * (gh[m][4 + d][q] + bhhn));
                float hv = bf2f(*(const short*)(lds + 33280 + ((row * 512 + j * 2) ^ ((row & 7) << 4))));
                float o = (1.f - z) * n + z * hv;
                *(float*)(lds + (row * 260 + j) * 4) = o;   // O pitch 260 f32
            }
        }
    }
    __syncthreads();

    // ---- LayerNorm + scatter: wave w handles rows 4w..4w+3
    #pragma unroll
    for (int rr = 0; rr < 4; ++rr) {
        int row = w * 4 + rr;
        f32x4 x = *(const f32x4*)(lds + (row * 260 + lane * 4) * 4);
        float s1 = x[0] + x[1] + x[2] + x[3];
        float s2 = x[0]*x[0] + x[1]*x[1] + x[2]*x[2] + x[3]*x[3];
        #pragma unroll
        for (int mm = 32; mm > 0; mm >>= 1) {
            s1 += __shfl_xor(s1, mm);
            s2 += __shfl_xor(s2, mm);
        }
        float mu  = s1 * (1.f / 256.f);
        float var = fmaxf(s2 * (1.f / 256.f) - mu * mu, 0.f);
        float inv = rsqrtf(var + 1e-5f);
        f32x4 g  = *(const f32x4*)(gamma + lane * 4);
        f32x4 be = *(const f32x4*)(beta  + lane * 4);
        int id = ids[base + row];
        f32x4 y;
        #pragma unroll
        for (int c = 0; c < 4; ++c) y[c] = (x[c] - mu) * inv * g[c] + be[c];
        *(f32x4*)(out_mem + (size_t)id * MEMH + lane * 4) = y;
        if (lane == 0) out_lu[id] = ts[base + row];
    }
}

// ------------------------------------------------------------------- launcher
extern "C" void kernel_launch(void* const* d_in, const int* in_sizes, int n_in,
                              void* d_out, int out_size, void* d_ws, size_t ws_size,
                              hipStream_t stream) {
    (void)n_in; (void)out_size;
    const int*   ids = (const int*)  d_in[0];
    const float* msg = (const float*)d_in[1];
    const float* ts  = (const float*)d_in[2];
    const float* mem = (const float*)d_in[3];
    const float* lu  = (const float*)d_in[4];
    const float* Wih = (const float*)d_in[5];
    const float* Whh = (const float*)d_in[6];
    const float* bih = (const float*)d_in[7];
    const float* bhh = (const float*)d_in[8];
    const float* gam = (const float*)d_in[9];
    const float* bet = (const float*)d_in[10];

    const int  n_upd   = in_sizes[0];                 // 65536
    const long n_nodes = (long)in_sizes[3] / MEMH;    // 500000

    float* out_mem = (float*)d_out;
    float* out_lu  = out_mem + (size_t)n_nodes * MEMH;

    const size_t w_need = (size_t)W_TOT_ELEMS * sizeof(short);
    const bool use_ws = (d_ws != nullptr) && (ws_size >= w_need);

    if (use_ws) {
        smu_cvtw_kernel<<<(W_TOT_ELEMS + 255) / 256, 256, 0, stream>>>(Wih, Whh, (short*)d_ws);
    }

    long n_mem4 = n_nodes * (MEMH / 4);   // 32,000,000
    long n_lu4  = n_nodes / 4;            // 125,000 (500000 % 4 == 0)
    smu_copy_kernel<<<2048, 256, 0, stream>>>((const float4*)mem, (const float4*)lu,
                                              (float4*)out_mem,
                                              (float4*)(out_mem + (size_t)n_nodes * MEMH),
                                              n_mem4, n_lu4);

    int grid = n_upd / 32;   // 65536/32 = 2048 (n_upd is a multiple of 32)
    if (use_ws) {
        smu_gru_kernel<true><<<grid, 512, 0, stream>>>(ids, msg, ts, mem, Wih, Whh, bih, bhh,
                                                       gam, bet, (const short*)d_ws,
                                                       out_mem, out_lu);
    } else {
        smu_gru_kernel<false><<<grid, 512, 0, stream>>>(ids, msg, ts, mem, Wih, Whh, bih, bhh,
                                                        gam, bet, nullptr,
                                                        out_mem, out_lu);
    }
}

// Round 3
// 458.195 us; speedup vs baseline: 1.2814x; 1.2814x over previous
//
#include <hip/hip_runtime.h>
#include <hip/hip_bf16.h>

typedef float  f32x4 __attribute__((ext_vector_type(4)));
typedef short  s16x8 __attribute__((ext_vector_type(8)));

#define MEMH   256        // mem_dim
#define MSGD   512        // msg_dim
#define G3     768        // 3*H
#define W_IH_ELEMS (G3*MSGD)        // 393216
#define W_HH_ELEMS (G3*MEMH)        // 196608
#define W_TOT_ELEMS (W_IH_ELEMS + W_HH_ELEMS)  // 589824
#define W_BYTES    ((size_t)W_TOT_ELEMS * 2)   // 1179648

#define BM     64         // rows per block
#define NTHR   1024       // 16 waves
#define AH_OFF 0          // A_h: 64x256 bf16, pitch 512 B  -> 32768 B
#define AM_OFF 32768      // A_msg: 64x512 bf16, pitch 1024 B -> 65536 B
#define O_OFF  32768      // O fp32 64x260 (pitch 1040 B) reuses A_msg region
#define LDS_BYTES (32768 + 66560)   // 99328

static __device__ __forceinline__ short f2bf(float x) {
    __hip_bfloat16 b = __float2bfloat16(x);
    return __builtin_bit_cast(short, b);
}
static __device__ __forceinline__ float bf2f(short s) {
    unsigned int u = ((unsigned int)(unsigned short)s) << 16;
    return __builtin_bit_cast(float, u);
}
static __device__ __forceinline__ float sigf(float x) {
    return 1.f / (1.f + __expf(-x));
}
static __device__ __forceinline__ float tanh_fast(float x) {
    float e = __expf(-2.f * fabsf(x));
    float t = (1.f - e) / (1.f + e);
    return copysignf(t, x);
}
static __device__ __forceinline__ f32x4 ntload4(const float* p) {
    return __builtin_nontemporal_load((const f32x4*)p);
}
static __device__ __forceinline__ void ntstore4(float* p, f32x4 v) {
    __builtin_nontemporal_store(v, (f32x4*)p);
}

// ---------------------------------------------------------------- copy kernel (fallback path only)
__global__ void smu_copy_kernel(const float* __restrict__ mem,
                                const float* __restrict__ lu,
                                float* __restrict__ out_mem,
                                float* __restrict__ out_lu,
                                long n_mem4, long n_lu4) {
    long i = (long)blockIdx.x * blockDim.x + threadIdx.x;
    long stride = (long)gridDim.x * blockDim.x;
    long total = n_mem4 + n_lu4;
    for (; i < total; i += stride) {
        if (i < n_mem4) ntstore4(out_mem + i * 4, ntload4(mem + i * 4));
        else {
            long j = (i - n_mem4) * 4;
            ntstore4(out_lu + j, ntload4(lu + j));
        }
    }
}

// --------------------------------------------------- weight fp32->bf16 kernel
__global__ void smu_cvtw_kernel(const float* __restrict__ wih,
                                const float* __restrict__ whh,
                                short* __restrict__ o) {
    int i = blockIdx.x * blockDim.x + threadIdx.x;
    if (i < W_IH_ELEMS)       o[i] = f2bf(wih[i]);
    else if (i < W_TOT_ELEMS) o[i] = f2bf(whh[i - W_IH_ELEMS]);
}

// --------------------------------------------------- bitmap of updated ids
__global__ void smu_bits_kernel(const int* __restrict__ ids,
                                unsigned* __restrict__ bm, int n) {
    int i = blockIdx.x * blockDim.x + threadIdx.x;
    if (i < n) {
        int id = ids[i];
        atomicOr(&bm[id >> 5], 1u << (id & 31));
    }
}

// ------------------------------------------------------------ B-frag loader
template<bool USE_WS>
static __device__ __forceinline__ s16x8 load_b(const float* __restrict__ Wf,
                                               const short* __restrict__ Wb,
                                               int row, int ldk, int kofs) {
    if constexpr (USE_WS) {
        return *(const s16x8*)(Wb + (size_t)row * ldk + kofs);
    } else {
        f32x4 x = *(const f32x4*)(Wf + (size_t)row * ldk + kofs);
        f32x4 y = *(const f32x4*)(Wf + (size_t)row * ldk + kofs + 4);
        s16x8 s;
        s[0]=f2bf(x[0]); s[1]=f2bf(x[1]); s[2]=f2bf(x[2]); s[3]=f2bf(x[3]);
        s[4]=f2bf(y[0]); s[5]=f2bf(y[1]); s[6]=f2bf(y[2]); s[7]=f2bf(y[3]);
        return s;
    }
}

// --------------------------------------------------------------- fused GRU+LN (+copy)
// Block: 1024 threads (16 waves), BM=64 rows. Wave w owns gate-tiles
// {w, w+16, w+32} of both gi and gh -> per lane a single output column
// j = w*16 + (lane&15) with r/z/n in registers. 4 m-tiles (rows 0..63).
// LDS: A_h bf16 [0,32768), A_msg bf16 [32768, 98304) reused as O fp32
// 64x260 in the epilogue.
template<bool USE_WS, bool FUSED>
__global__ __launch_bounds__(NTHR, 1)
void smu_gru_kernel(const int*   __restrict__ ids,
                    const float* __restrict__ msg,
                    const float* __restrict__ ts,
                    const float* __restrict__ memory,
                    const float* __restrict__ lu,
                    const float* __restrict__ W_ih,
                    const float* __restrict__ W_hh,
                    const float* __restrict__ b_ih,
                    const float* __restrict__ b_hh,
                    const float* __restrict__ gamma,
                    const float* __restrict__ beta,
                    const short* __restrict__ wsw,
                    const unsigned* __restrict__ bm,
                    float* __restrict__ out_mem,
                    float* __restrict__ out_lu,
                    long n_nodes) {
    __shared__ __align__(16) unsigned char lds[LDS_BYTES];
    const int tid  = threadIdx.x;
    const int bid  = blockIdx.x;
    const long base = (long)bid * BM;

    // ================= copy phase (order alternates by block parity)
    auto copy_phase = [&]() {
        if constexpr (FUSED) {
            // memory rows: 32 rows per group, 32 threads/row, 2 f32x4/thread
            const long RG = 32;
            long ng  = (n_nodes + RG - 1) / RG;
            long per = (ng + gridDim.x - 1) / gridDim.x;
            long gs  = (long)bid * per;
            long ge  = gs + per < ng ? gs + per : ng;
            for (long g = gs; g < ge; ++g) {
                long row = g * RG + (tid >> 5);
                if (row < n_nodes && !((bm[row >> 5] >> (row & 31)) & 1u)) {
                    const float* s = memory + row * MEMH + (tid & 31) * 8;
                    f32x4 v0 = ntload4(s);
                    f32x4 v1 = ntload4(s + 4);
                    float* d = out_mem + row * MEMH + (tid & 31) * 8;
                    ntstore4(d, v0);
                    ntstore4(d + 4, v1);
                }
            }
            // last_update
            for (long i = (long)bid * NTHR + tid; i < n_nodes; i += (long)gridDim.x * NTHR) {
                if (!((bm[i >> 5] >> (i & 31)) & 1u)) {
                    float v = __builtin_nontemporal_load(lu + i);
                    __builtin_nontemporal_store(v, out_lu + i);
                }
            }
        }
    };

    // ================= GRU phase
    auto gru_phase = [&]() {
        // ---- stage A_msg: 64x512 f32 -> bf16 (4096 8-elem units, 4/thread)
        {
            const float* src = msg + base * MSGD;
            #pragma unroll
            for (int it = 0; it < 4; ++it) {
                int u = tid + NTHR * it;         // 0..4095
                int row = u >> 6;                // 64 units per row
                f32x4 a = ntload4(src + u * 8);
                f32x4 b = ntload4(src + u * 8 + 4);
                s16x8 s;
                s[0]=f2bf(a[0]); s[1]=f2bf(a[1]); s[2]=f2bf(a[2]); s[3]=f2bf(a[3]);
                s[4]=f2bf(b[0]); s[5]=f2bf(b[1]); s[6]=f2bf(b[2]); s[7]=f2bf(b[3]);
                int byte = AM_OFF + ((u * 16) ^ ((row & 7) << 4)); // u*16 == row*1024 + c*16
                *(s16x8*)(lds + byte) = s;
            }
            // ---- stage A_h (gather): 64x256 (2048 units, 2/thread)
            #pragma unroll
            for (int it = 0; it < 2; ++it) {
                int u = tid + NTHR * it;         // 0..2047
                int row = u >> 5;                // 32 units per row
                int c8  = u & 31;
                int id  = ids[base + row];
                const float* hs = memory + (size_t)id * MEMH + c8 * 8;
                f32x4 a = ntload4(hs);
                f32x4 b = ntload4(hs + 4);
                s16x8 s;
                s[0]=f2bf(a[0]); s[1]=f2bf(a[1]); s[2]=f2bf(a[2]); s[3]=f2bf(a[3]);
                s[4]=f2bf(b[0]); s[5]=f2bf(b[1]); s[6]=f2bf(b[2]); s[7]=f2bf(b[3]);
                int byte = AH_OFF + ((u * 16) ^ ((row & 7) << 4)); // u*16 == row*512 + c8*16
                *(s16x8*)(lds + byte) = s;
            }
        }
        __syncthreads();

        const int lane = tid & 63;
        const int w    = tid >> 6;              // 0..15
        const int lr   = lane & 15;
        const int lk8  = (lane >> 4) * 8;       // k offset within 32-wide ktile
        const int sw   = (lr & 7) << 4;
        const short* Wi = wsw;
        const short* Wh = wsw + W_IH_ELEMS;
        const int rowW = w * 16 + lr;           // +256*i for gate i

        f32x4 gi[4][3] = {};
        f32x4 gh[4][3] = {};

        // ---- GEMM 1: gi += msg @ W_ih^T  (K=512, 16 ktiles, depth-2 B prefetch)
        {
            s16x8 b[2][3];
            #pragma unroll
            for (int i = 0; i < 3; ++i) b[0][i] = load_b<USE_WS>(W_ih, Wi, rowW + 256*i, MSGD, lk8);
            #pragma unroll
            for (int i = 0; i < 3; ++i) b[1][i] = load_b<USE_WS>(W_ih, Wi, rowW + 256*i, MSGD, 32 + lk8);
            #pragma unroll
            for (int k = 0; k < 16; ++k) {
                const int cb = (k * 32 + lk8) * 2;
                s16x8 a[4];
                #pragma unroll
                for (int m = 0; m < 4; ++m)
                    a[m] = *(const s16x8*)(lds + AM_OFF + (((m*16 + lr) * 1024 + cb) ^ sw));
                #pragma unroll
                for (int i = 0; i < 3; ++i)
                    #pragma unroll
                    for (int m = 0; m < 4; ++m)
                        gi[m][i] = __builtin_amdgcn_mfma_f32_16x16x32_bf16(a[m], b[k & 1][i], gi[m][i], 0, 0, 0);
                if (k < 14) {
                    const int ko = (k + 2) * 32 + lk8;
                    #pragma unroll
                    for (int i = 0; i < 3; ++i)
                        b[k & 1][i] = load_b<USE_WS>(W_ih, Wi, rowW + 256*i, MSGD, ko);
                }
            }
        }
        // ---- GEMM 2: gh += h @ W_hh^T  (K=256, 8 ktiles)
        {
            s16x8 b[2][3];
            #pragma unroll
            for (int i = 0; i < 3; ++i) b[0][i] = load_b<USE_WS>(W_hh, Wh, rowW + 256*i, MEMH, lk8);
            #pragma unroll
            for (int i = 0; i < 3; ++i) b[1][i] = load_b<USE_WS>(W_hh, Wh, rowW + 256*i, MEMH, 32 + lk8);
            #pragma unroll
            for (int k = 0; k < 8; ++k) {
                const int cb = (k * 32 + lk8) * 2;
                s16x8 a[4];
                #pragma unroll
                for (int m = 0; m < 4; ++m)
                    a[m] = *(const s16x8*)(lds + AH_OFF + (((m*16 + lr) * 512 + cb) ^ sw));
                #pragma unroll
                for (int i = 0; i < 3; ++i)
                    #pragma unroll
                    for (int m = 0; m < 4; ++m)
                        gh[m][i] = __builtin_amdgcn_mfma_f32_16x16x32_bf16(a[m], b[k & 1][i], gh[m][i], 0, 0, 0);
                if (k < 6) {
                    const int ko = (k + 2) * 32 + lk8;
                    #pragma unroll
                    for (int i = 0; i < 3; ++i)
                        b[k & 1][i] = load_b<USE_WS>(W_hh, Wh, rowW + 256*i, MEMH, ko);
                }
            }
        }

        __syncthreads();   // all A_msg reads done before O overwrites region

        // ---- gate epilogue: C layout col=lane&15, row=(lane>>4)*4+q
        {
            const int lq = (lane >> 4) * 4;
            const int j  = w * 16 + lr;          // this lane's output column
            const float bihr = b_ih[j],       bhhr = b_hh[j];
            const float bihz = b_ih[256 + j], bhhz = b_hh[256 + j];
            const float bihn = b_ih[512 + j], bhhn = b_hh[512 + j];
            #pragma unroll
            for (int m = 0; m < 4; ++m) {
                #pragma unroll
                for (int q = 0; q < 4; ++q) {
                    int row = m * 16 + lq + q;
                    float r = sigf(gi[m][0][q] + gh[m][0][q] + bihr + bhhr);
                    float z = sigf(gi[m][1][q] + gh[m][1][q] + bihz + bhhz);
                    float n = tanh_fast(gi[m][2][q] + bihn + r * (gh[m][2][q] + bhhn));
                    float hv = bf2f(*(const short*)(lds + AH_OFF + ((row * 512 + j * 2) ^ ((row & 7) << 4))));
                    float o = (1.f - z) * n + z * hv;
                    *(float*)(lds + O_OFF + (row * 260 + j) * 4) = o;
                }
            }
        }
        __syncthreads();

        // ---- LayerNorm + scatter: wave w handles rows 4w..4w+3
        #pragma unroll
        for (int rr = 0; rr < 4; ++rr) {
            int row = w * 4 + rr;
            f32x4 x = *(const f32x4*)(lds + O_OFF + (row * 260 + lane * 4) * 4);
            float s1 = x[0] + x[1] + x[2] + x[3];
            float s2 = x[0]*x[0] + x[1]*x[1] + x[2]*x[2] + x[3]*x[3];
            #pragma unroll
            for (int mm = 32; mm > 0; mm >>= 1) {
                s1 += __shfl_xor(s1, mm);
                s2 += __shfl_xor(s2, mm);
            }
            float mu  = s1 * (1.f / 256.f);
            float var = fmaxf(s2 * (1.f / 256.f) - mu * mu, 0.f);
            float inv = rsqrtf(var + 1e-5f);
            f32x4 g  = *(const f32x4*)(gamma + lane * 4);
            f32x4 be = *(const f32x4*)(beta  + lane * 4);
            int id = ids[base + row];
            f32x4 y;
            #pragma unroll
            for (int c = 0; c < 4; ++c) y[c] = (x[c] - mu) * inv * g[c] + be[c];
            ntstore4(out_mem + (size_t)id * MEMH + lane * 4, y);
            if (lane == 0) __builtin_nontemporal_store(ts[base + row], out_lu + id);
        }
    };

    if constexpr (FUSED) {
        if (bid & 1) { copy_phase(); gru_phase(); }
        else         { gru_phase(); copy_phase(); }
    } else {
        gru_phase();
    }
}

// ------------------------------------------------------------------- launcher
extern "C" void kernel_launch(void* const* d_in, const int* in_sizes, int n_in,
                              void* d_out, int out_size, void* d_ws, size_t ws_size,
                              hipStream_t stream) {
    (void)n_in; (void)out_size;
    const int*   ids = (const int*)  d_in[0];
    const float* msg = (const float*)d_in[1];
    const float* ts  = (const float*)d_in[2];
    const float* mem = (const float*)d_in[3];
    const float* lu  = (const float*)d_in[4];
    const float* Wih = (const float*)d_in[5];
    const float* Whh = (const float*)d_in[6];
    const float* bih = (const float*)d_in[7];
    const float* bhh = (const float*)d_in[8];
    const float* gam = (const float*)d_in[9];
    const float* bet = (const float*)d_in[10];

    const int  n_upd   = in_sizes[0];                 // 65536
    const long n_nodes = (long)in_sizes[3] / MEMH;    // 500000

    float* out_mem = (float*)d_out;
    float* out_lu  = out_mem + (size_t)n_nodes * MEMH;

    const size_t bm_words = (size_t)((n_nodes + 31) / 32);
    const size_t bm_bytes = bm_words * 4;
    const bool ws_w  = (d_ws != nullptr) && (ws_size >= W_BYTES);
    const bool ws_bm = (d_ws != nullptr) && (ws_size >= W_BYTES + bm_bytes);

    short*    wsw = (short*)d_ws;
    unsigned* bm  = (unsigned*)((char*)d_ws + W_BYTES);

    if (ws_w) {
        smu_cvtw_kernel<<<(W_TOT_ELEMS + 255) / 256, 256, 0, stream>>>(Wih, Whh, wsw);
    }
    if (ws_bm) {
        (void)hipMemsetAsync(bm, 0, bm_bytes, stream);
        smu_bits_kernel<<<(n_upd + 255) / 256, 256, 0, stream>>>(ids, bm, n_upd);
    }

    const int grid = n_upd / BM;   // 65536/64 = 1024

    if (ws_bm) {
        // fused: copy (bitmap-skipped) + GRU in one kernel
        smu_gru_kernel<true, true><<<grid, NTHR, 0, stream>>>(
            ids, msg, ts, mem, lu, Wih, Whh, bih, bhh, gam, bet,
            wsw, bm, out_mem, out_lu, n_nodes);
    } else {
        // fallback: full copy first, then GRU scatter
        long n_mem4 = n_nodes * (MEMH / 4);
        long n_lu4  = n_nodes / 4;
        smu_copy_kernel<<<2048, 256, 0, stream>>>(mem, lu, out_mem, out_lu,
                                                  n_mem4, n_lu4);
        if (ws_w) {
            smu_gru_kernel<true, false><<<grid, NTHR, 0, stream>>>(
                ids, msg, ts, mem, lu, Wih, Whh, bih, bhh, gam, bet,
                wsw, nullptr, out_mem, out_lu, n_nodes);
        } else {
            smu_gru_kernel<false, false><<<grid, NTHR, 0, stream>>>(
                ids, msg, ts, mem, lu, Wih, Whh, bih, bhh, gam, bet,
                nullptr, nullptr, out_mem, out_lu, n_nodes);
        }
    }
}

// Round 4
// 386.325 us; speedup vs baseline: 1.5198x; 1.1860x over previous
//
#include <hip/hip_runtime.h>
#include <hip/hip_bf16.h>

typedef float  f32x4 __attribute__((ext_vector_type(4)));
typedef short  s16x8 __attribute__((ext_vector_type(8)));

#define MEMH   256        // mem_dim
#define MSGD   512        // msg_dim
#define G3     768        // 3*H
#define W_IH_ELEMS (G3*MSGD)        // 393216
#define W_HH_ELEMS (G3*MEMH)        // 196608
#define W_TOT_ELEMS (W_IH_ELEMS + W_HH_ELEMS)  // 589824
#define W_BYTES    ((size_t)W_TOT_ELEMS * 2)   // 1179648

#define BM     64         // rows per block
#define NTHR   1024       // 16 waves
#define AH_OFF 0          // A_h: 64x256 bf16, pitch 512 B  -> 32768 B
#define AM_OFF 32768      // A_msg: 64x512 bf16, pitch 1024 B -> 65536 B
#define O_OFF  32768      // O fp32 64x260 (pitch 1040 B) reuses A_msg region
#define LDS_BYTES (32768 + 66560)   // 99328

static __device__ __forceinline__ short f2bf(float x) {
    __hip_bfloat16 b = __float2bfloat16(x);
    return __builtin_bit_cast(short, b);
}
static __device__ __forceinline__ float bf2f(short s) {
    unsigned int u = ((unsigned int)(unsigned short)s) << 16;
    return __builtin_bit_cast(float, u);
}
static __device__ __forceinline__ float sigf(float x) {
    return 1.f / (1.f + __expf(-x));
}
static __device__ __forceinline__ float tanh_fast(float x) {
    float e = __expf(-2.f * fabsf(x));
    float t = (1.f - e) / (1.f + e);
    return copysignf(t, x);
}
static __device__ __forceinline__ f32x4 ntload4(const float* p) {
    return __builtin_nontemporal_load((const f32x4*)p);
}
static __device__ __forceinline__ void ntstore4(float* p, f32x4 v) {
    __builtin_nontemporal_store(v, (f32x4*)p);
}

// ---------------------------------------------------------------- copy kernel (fallback path only)
__global__ void smu_copy_kernel(const float* __restrict__ mem,
                                const float* __restrict__ lu,
                                float* __restrict__ out_mem,
                                float* __restrict__ out_lu,
                                long n_mem4, long n_lu4) {
    long i = (long)blockIdx.x * blockDim.x + threadIdx.x;
    long stride = (long)gridDim.x * blockDim.x;
    long total = n_mem4 + n_lu4;
    for (; i < total; i += stride) {
        if (i < n_mem4) ntstore4(out_mem + i * 4, ntload4(mem + i * 4));
        else {
            long j = (i - n_mem4) * 4;
            ntstore4(out_lu + j, ntload4(lu + j));
        }
    }
}

// --------------------------------------------------- weight fp32->bf16 PACKED fragment layout
// ih: frag (t in [0,48), k in [0,16)) at elem off (t*16+k)*512; within frag
// elem idx = l*8+e  ->  source row t*16+(l&15), col k*32+(l>>4)*8+e.
// hh: frag (t in [0,48), k in [0,8)) at W_IH_ELEMS + (t*8+k)*512, same inner map.
__global__ void smu_cvtw_kernel(const float* __restrict__ wih,
                                const float* __restrict__ whh,
                                short* __restrict__ o) {
    int i = blockIdx.x * blockDim.x + threadIdx.x;
    if (i >= W_TOT_ELEMS) return;
    if (i < W_IH_ELEMS) {
        int f = i >> 9, r = i & 511, l = r >> 3, e = r & 7;
        int t = f >> 4, k = f & 15;
        int row = t * 16 + (l & 15), col = k * 32 + (l >> 4) * 8 + e;
        o[i] = f2bf(wih[row * MSGD + col]);
    } else {
        int j = i - W_IH_ELEMS;
        int f = j >> 9, r = j & 511, l = r >> 3, e = r & 7;
        int t = f >> 3, k = f & 7;
        int row = t * 16 + (l & 15), col = k * 32 + (l >> 4) * 8 + e;
        o[i] = f2bf(whh[row * MEMH + col]);
    }
}

// --------------------------------------------------- bitmap of updated ids
__global__ void smu_bits_kernel(const int* __restrict__ ids,
                                unsigned* __restrict__ bm, int n) {
    int i = blockIdx.x * blockDim.x + threadIdx.x;
    if (i < n) {
        int id = ids[i];
        atomicOr(&bm[id >> 5], 1u << (id & 31));
    }
}

// ------------------------------------------------------------ B-frag loader
// packed path: one contiguous 1KB wave load. fallback: scattered f32 converts.
template<bool USE_WS>
static __device__ __forceinline__ s16x8 load_b(const float* __restrict__ Wf,
                                               const short* __restrict__ Wb,
                                               int t, int k, int ldk, int nkt, int lane) {
    if constexpr (USE_WS) {
        return *(const s16x8*)(Wb + ((size_t)(t * nkt + k) << 9) + lane * 8);
    } else {
        int row = t * 16 + (lane & 15);
        int col = k * 32 + (lane >> 4) * 8;
        f32x4 x = *(const f32x4*)(Wf + (size_t)row * ldk + col);
        f32x4 y = *(const f32x4*)(Wf + (size_t)row * ldk + col + 4);
        s16x8 s;
        s[0]=f2bf(x[0]); s[1]=f2bf(x[1]); s[2]=f2bf(x[2]); s[3]=f2bf(x[3]);
        s[4]=f2bf(y[0]); s[5]=f2bf(y[1]); s[6]=f2bf(y[2]); s[7]=f2bf(y[3]);
        return s;
    }
}

// copy-pipe macros: batch = 2 rows held in regs; store happens 2 k-steps later.
#define CP_LOAD(BUF, s) do { if constexpr (FUSED) {                                   \
    const int lo_ = (s) * 2;                                                          \
    const long o0_ = (long)w * 48 + lo_;                                              \
    const long r0_ = crow_base + o0_;                                                 \
    cpf_##BUF##0 = (o0_ < cpslab) && (r0_ < n_nodes) && !((cpwin >> lo_) & 1);        \
    cpf_##BUF##1 = (o0_ + 1 < cpslab) && (r0_ + 1 < n_nodes) && !((cpwin >> (lo_ + 1)) & 1); \
    if (cpf_##BUF##0) cpv_##BUF##0 = ntload4(memory + r0_ * MEMH + (lane << 2));      \
    if (cpf_##BUF##1) cpv_##BUF##1 = ntload4(memory + (r0_ + 1) * MEMH + (lane << 2));\
  } } while (0)

#define CP_STORE(BUF, s) do { if constexpr (FUSED) {                                  \
    const long r0_ = crow_base + (long)w * 48 + (s) * 2;                              \
    if (cpf_##BUF##0) ntstore4(out_mem + r0_ * MEMH + (lane << 2), cpv_##BUF##0);     \
    if (cpf_##BUF##1) ntstore4(out_mem + (r0_ + 1) * MEMH + (lane << 2), cpv_##BUF##1);\
    cpf_##BUF##0 = false; cpf_##BUF##1 = false;                                       \
  } } while (0)

// --------------------------------------------------------------- fused GRU+LN+copy
// Block: 1024 threads (16 waves), BM=64 rows. Wave w owns gate-tiles
// t = w+16i (i = r,z,n). Accs: acc[m][0]=r-sum, acc[m][1]=z-sum,
// acc[m][2]=gi_n, accn[m]=gh_n  (GEMM2 adds r,z into acc[m][0..1]).
// Copy of non-updated memory rows is pipelined through the 24 k-steps.
template<bool USE_WS, bool FUSED>
__global__ __launch_bounds__(NTHR, 1)
void smu_gru_kernel(const int*   __restrict__ ids,
                    const float* __restrict__ msg,
                    const float* __restrict__ ts,
                    const float* __restrict__ memory,
                    const float* __restrict__ lu,
                    const float* __restrict__ W_ih,
                    const float* __restrict__ W_hh,
                    const float* __restrict__ b_ih,
                    const float* __restrict__ b_hh,
                    const float* __restrict__ gamma,
                    const float* __restrict__ beta,
                    const short* __restrict__ wsw,
                    const unsigned* __restrict__ bm,
                    float* __restrict__ out_mem,
                    float* __restrict__ out_lu,
                    long n_nodes, long cpslab) {
    __shared__ __align__(16) unsigned char lds[LDS_BYTES];
    const int tid  = threadIdx.x;
    const int bid  = blockIdx.x;
    const long base = (long)bid * BM;
    const long crow_base = (long)bid * cpslab;

    // ---- stage A_msg: 64x512 f32 -> bf16 (4096 8-elem units, 4/thread)
    {
        const float* src = msg + base * MSGD;
        #pragma unroll
        for (int it = 0; it < 4; ++it) {
            int u = tid + NTHR * it;         // 0..4095
            int row = u >> 6;                // 64 units per row
            f32x4 a = ntload4(src + u * 8);
            f32x4 b = ntload4(src + u * 8 + 4);
            s16x8 s;
            s[0]=f2bf(a[0]); s[1]=f2bf(a[1]); s[2]=f2bf(a[2]); s[3]=f2bf(a[3]);
            s[4]=f2bf(b[0]); s[5]=f2bf(b[1]); s[6]=f2bf(b[2]); s[7]=f2bf(b[3]);
            int byte = AM_OFF + ((u * 16) ^ ((row & 7) << 4));
            *(s16x8*)(lds + byte) = s;
        }
        // ---- stage A_h (gather): 64x256 (2048 units, 2/thread)
        #pragma unroll
        for (int it = 0; it < 2; ++it) {
            int u = tid + NTHR * it;         // 0..2047
            int row = u >> 5;                // 32 units per row
            int c8  = u & 31;
            int id  = ids[base + row];
            const float* hs = memory + (size_t)id * MEMH + c8 * 8;
            f32x4 a = ntload4(hs);
            f32x4 b = ntload4(hs + 4);
            s16x8 s;
            s[0]=f2bf(a[0]); s[1]=f2bf(a[1]); s[2]=f2bf(a[2]); s[3]=f2bf(a[3]);
            s[4]=f2bf(b[0]); s[5]=f2bf(b[1]); s[6]=f2bf(b[2]); s[7]=f2bf(b[3]);
            int byte = AH_OFF + ((u * 16) ^ ((row & 7) << 4));
            *(s16x8*)(lds + byte) = s;
        }
    }
    __syncthreads();

    const int lane = tid & 63;
    const int w    = tid >> 6;              // 0..15
    const int lr   = lane & 15;
    const int lk8  = (lane >> 4) * 8;       // k offset within 32-wide ktile
    const int sw   = (lr & 7) << 4;
    const short* Wi = wsw;
    const short* Wh = wsw + W_IH_ELEMS;

    // ---- copy-pipe state + per-wave 48-bit skip window
    f32x4 cpv_A0, cpv_A1, cpv_B0, cpv_B1;
    bool  cpf_A0 = false, cpf_A1 = false, cpf_B0 = false, cpf_B1 = false;
    unsigned long long cpwin = 0;
    if constexpr (FUSED) {
        long start = crow_base + (long)w * 48;
        long wi = start >> 5;
        int  off = (int)(start & 31);
        unsigned b0 = bm[wi], b1 = bm[wi + 1], b2 = bm[wi + 2];   // bm is padded
        unsigned long long lo64 = ((unsigned long long)b1 << 32) | b0;
        cpwin = lo64 >> off;
        if (off) cpwin |= ((unsigned long long)b2) << (64 - off);
    }

    f32x4 acc[4][3] = {};   // [m][0]=r-sum  [1]=z-sum  [2]=gi_n
    f32x4 accn[4]   = {};   // gh_n

    // ---- GEMM 1: msg @ W_ih^T  (K=512, 16 ktiles, s = 0..15)
    {
        s16x8 b[2][3];
        #pragma unroll
        for (int i = 0; i < 3; ++i) b[0][i] = load_b<USE_WS>(W_ih, Wi, w + 16*i, 0, MSGD, 16, lane);
        #pragma unroll
        for (int i = 0; i < 3; ++i) b[1][i] = load_b<USE_WS>(W_ih, Wi, w + 16*i, 1, MSGD, 16, lane);
        #pragma unroll
        for (int k = 0; k < 16; ++k) {
            if ((k & 1) == 0) { CP_STORE(A, k - 2); CP_LOAD(A, k); }
            else              { CP_STORE(B, k - 2); CP_LOAD(B, k); }
            const int cb = (k * 32 + lk8) * 2;
            #pragma unroll
            for (int m = 0; m < 4; ++m) {
                s16x8 a = *(const s16x8*)(lds + AM_OFF + (((m*16 + lr) * 1024 + cb) ^ sw));
                #pragma unroll
                for (int i = 0; i < 3; ++i)
                    acc[m][i] = __builtin_amdgcn_mfma_f32_16x16x32_bf16(a, b[k & 1][i], acc[m][i], 0, 0, 0);
            }
            if (k < 14) {
                #pragma unroll
                for (int i = 0; i < 3; ++i)
                    b[k & 1][i] = load_b<USE_WS>(W_ih, Wi, w + 16*i, k + 2, MSGD, 16, lane);
            }
        }
    }
    // ---- GEMM 2: h @ W_hh^T  (K=256, 8 ktiles, s = 16..23)
    {
        s16x8 b[2][3];
        #pragma unroll
        for (int i = 0; i < 3; ++i) b[0][i] = load_b<USE_WS>(W_hh, Wh, w + 16*i, 0, MEMH, 8, lane);
        #pragma unroll
        for (int i = 0; i < 3; ++i) b[1][i] = load_b<USE_WS>(W_hh, Wh, w + 16*i, 1, MEMH, 8, lane);
        #pragma unroll
        for (int k = 0; k < 8; ++k) {
            if ((k & 1) == 0) { CP_STORE(A, 14 + k); CP_LOAD(A, 16 + k); }
            else              { CP_STORE(B, 14 + k); CP_LOAD(B, 16 + k); }
            const int cb = (k * 32 + lk8) * 2;
            #pragma unroll
            for (int m = 0; m < 4; ++m) {
                s16x8 a = *(const s16x8*)(lds + AH_OFF + (((m*16 + lr) * 512 + cb) ^ sw));
                acc[m][0] = __builtin_amdgcn_mfma_f32_16x16x32_bf16(a, b[k & 1][0], acc[m][0], 0, 0, 0);
                acc[m][1] = __builtin_amdgcn_mfma_f32_16x16x32_bf16(a, b[k & 1][1], acc[m][1], 0, 0, 0);
                accn[m]   = __builtin_amdgcn_mfma_f32_16x16x32_bf16(a, b[k & 1][2], accn[m],   0, 0, 0);
            }
            if (k < 6) {
                #pragma unroll
                for (int i = 0; i < 3; ++i)
                    b[k & 1][i] = load_b<USE_WS>(W_hh, Wh, w + 16*i, k + 2, MEMH, 8, lane);
            }
        }
    }
    // drain copy pipe (batches from steps 22 and 23)
    CP_STORE(A, 22);
    CP_STORE(B, 23);

    __syncthreads();   // all A_msg reads done before O overwrites region

    // ---- gate epilogue: C layout col=lane&15, row=(lane>>4)*4+q
    {
        const int lq = (lane >> 4) * 4;
        const int j  = w * 16 + lr;          // this lane's output column
        const float br = b_ih[j]       + b_hh[j];
        const float bz = b_ih[256 + j] + b_hh[256 + j];
        const float bihn = b_ih[512 + j], bhhn = b_hh[512 + j];
        #pragma unroll
        for (int m = 0; m < 4; ++m) {
            #pragma unroll
            for (int q = 0; q < 4; ++q) {
                int row = m * 16 + lq + q;
                float r = sigf(acc[m][0][q] + br);
                float z = sigf(acc[m][1][q] + bz);
                float n = tanh_fast(acc[m][2][q] + bihn + r * (accn[m][q] + bhhn));
                float hv = bf2f(*(const short*)(lds + AH_OFF + ((row * 512 + j * 2) ^ ((row & 7) << 4))));
                float o = (1.f - z) * n + z * hv;
                *(float*)(lds + O_OFF + (row * 260 + j) * 4) = o;
            }
        }
    }
    __syncthreads();

    // ---- LayerNorm + scatter: wave w handles rows 4w..4w+3
    #pragma unroll
    for (int rr = 0; rr < 4; ++rr) {
        int row = w * 4 + rr;
        f32x4 x = *(const f32x4*)(lds + O_OFF + (row * 260 + lane * 4) * 4);
        float s1 = x[0] + x[1] + x[2] + x[3];
        float s2 = x[0]*x[0] + x[1]*x[1] + x[2]*x[2] + x[3]*x[3];
        #pragma unroll
        for (int mm = 32; mm > 0; mm >>= 1) {
            s1 += __shfl_xor(s1, mm);
            s2 += __shfl_xor(s2, mm);
        }
        float mu  = s1 * (1.f / 256.f);
        float var = fmaxf(s2 * (1.f / 256.f) - mu * mu, 0.f);
        float inv = rsqrtf(var + 1e-5f);
        f32x4 g  = *(const f32x4*)(gamma + lane * 4);
        f32x4 be = *(const f32x4*)(beta  + lane * 4);
        int id = ids[base + row];
        f32x4 y;
        #pragma unroll
        for (int c = 0; c < 4; ++c) y[c] = (x[c] - mu) * inv * g[c] + be[c];
        ntstore4(out_mem + (size_t)id * MEMH + lane * 4, y);
        if (lane == 0) __builtin_nontemporal_store(ts[base + row], out_lu + id);
    }

    // ---- tails: rows beyond the 768-row pipeline capacity (normally none) + last_update
    if constexpr (FUSED) {
        for (long o = 768 + w; o < cpslab; o += 16) {
            long row = crow_base + o;
            if (row < n_nodes && !((bm[row >> 5] >> (row & 31)) & 1u)) {
                f32x4 v = ntload4(memory + row * MEMH + (lane << 2));
                ntstore4(out_mem + row * MEMH + (lane << 2), v);
            }
        }
        for (long i = (long)bid * NTHR + tid; i < n_nodes; i += (long)gridDim.x * NTHR) {
            if (!((bm[i >> 5] >> (i & 31)) & 1u)) {
                float v = __builtin_nontemporal_load(lu + i);
                __builtin_nontemporal_store(v, out_lu + i);
            }
        }
    }
}

// ------------------------------------------------------------------- launcher
extern "C" void kernel_launch(void* const* d_in, const int* in_sizes, int n_in,
                              void* d_out, int out_size, void* d_ws, size_t ws_size,
                              hipStream_t stream) {
    (void)n_in; (void)out_size;
    const int*   ids = (const int*)  d_in[0];
    const float* msg = (const float*)d_in[1];
    const float* ts  = (const float*)d_in[2];
    const float* mem = (const float*)d_in[3];
    const float* lu  = (const float*)d_in[4];
    const float* Wih = (const float*)d_in[5];
    const float* Whh = (const float*)d_in[6];
    const float* bih = (const float*)d_in[7];
    const float* bhh = (const float*)d_in[8];
    const float* gam = (const float*)d_in[9];
    const float* bet = (const float*)d_in[10];

    const int  n_upd   = in_sizes[0];                 // 65536
    const long n_nodes = (long)in_sizes[3] / MEMH;    // 500000

    float* out_mem = (float*)d_out;
    float* out_lu  = out_mem + (size_t)n_nodes * MEMH;

    const size_t bm_words = (size_t)((n_nodes + 31) / 32);
    const size_t bm_bytes_pad = bm_words * 4 + 16;    // +16B so 3-word window reads are safe
    const bool ws_w  = (d_ws != nullptr) && (ws_size >= W_BYTES);
    const bool ws_bm = (d_ws != nullptr) && (ws_size >= W_BYTES + bm_bytes_pad);

    short*    wsw = (short*)d_ws;
    unsigned* bm  = (unsigned*)((char*)d_ws + W_BYTES);

    if (ws_w) {
        smu_cvtw_kernel<<<(W_TOT_ELEMS + 255) / 256, 256, 0, stream>>>(Wih, Whh, wsw);
    }
    if (ws_bm) {
        (void)hipMemsetAsync(bm, 0, bm_bytes_pad, stream);
        smu_bits_kernel<<<(n_upd + 255) / 256, 256, 0, stream>>>(ids, bm, n_upd);
    }

    const int  grid   = n_upd / BM;   // 65536/64 = 1024
    const long cpslab = (n_nodes + grid - 1) / grid;

    if (ws_bm) {
        smu_gru_kernel<true, true><<<grid, NTHR, 0, stream>>>(
            ids, msg, ts, mem, lu, Wih, Whh, bih, bhh, gam, bet,
            wsw, bm, out_mem, out_lu, n_nodes, cpslab);
    } else {
        long n_mem4 = n_nodes * (MEMH / 4);
        long n_lu4  = n_nodes / 4;
        smu_copy_kernel<<<2048, 256, 0, stream>>>(mem, lu, out_mem, out_lu,
                                                  n_mem4, n_lu4);
        if (ws_w) {
            smu_gru_kernel<true, false><<<grid, NTHR, 0, stream>>>(
                ids, msg, ts, mem, lu, Wih, Whh, bih, bhh, gam, bet,
                wsw, nullptr, out_mem, out_lu, n_nodes, cpslab);
        } else {
            smu_gru_kernel<false, false><<<grid, NTHR, 0, stream>>>(
                ids, msg, ts, mem, lu, Wih, Whh, bih, bhh, gam, bet,
                nullptr, nullptr, out_mem, out_lu, n_nodes, cpslab);
        }
    }
}